// Round 1
// baseline (219.186 us; speedup 1.0000x reference)
//
#include <hip/hip_runtime.h>

// SimpleGraphSAGE: out = mean_agg(x[src]->dst) @ W_l + b_l + x @ W_r
// N=50000, E=640000, IN=128, HID=256.
// R5: agg_k rework — prefetch up to 64 src indices per wave with ONE coalesced
//     load, broadcast via __shfl (register-only), 16 edges / 4 gathers in
//     flight per iteration (was 8 edges with a serial src->gather chain per
//     iteration). Everything else unchanged from R4.

constexpr int N_NODES = 50000;
constexpr int N_EDGES = 640000;
constexpr int IN_CH   = 128;
constexpr int HID_CH  = 256;
constexpr int SCAN_BLOCKS = (N_NODES + 256) / 256;  // 196, covers i==N_NODES

constexpr int HIST_BLOCKS  = N_EDGES / 1024;        // 625, thread handles 4 edges
constexpr int PREPX_BLOCKS = N_NODES * 32 / 256;    // 6250, thread = 4 channels
constexpr int WPREP_BLOCKS = 256;                   // 65536 weight elems

typedef __attribute__((ext_vector_type(8))) short short8;
typedef __attribute__((ext_vector_type(4))) float f32x4;

__device__ inline unsigned short f2bf(float f) {
    unsigned int u = __float_as_uint(f);
    u += 0x7fff + ((u >> 16) & 1);  // RNE
    return (unsigned short)(u >> 16);
}
__device__ inline float bf2f(unsigned int s) {
    return __uint_as_float(s << 16);
}

// ---------------------------------------------------------------------------
// prep_k: block-range fused  [hist | x->bf16 | W->bf16 tiled]
// ---------------------------------------------------------------------------
__global__ __launch_bounds__(256) void prep_k(const float* __restrict__ x,
                                              const int* __restrict__ ei,
                                              const float* __restrict__ Wl,
                                              const float* __restrict__ Wr,
                                              unsigned int* __restrict__ Abf_u,
                                              unsigned short* __restrict__ Wimg,
                                              int* __restrict__ cnt) {
    int bid = blockIdx.x, tid = threadIdx.x;
    if (bid < HIST_BLOCKS) {
        int base = bid * 1024 + tid;
#pragma unroll
        for (int k = 0; k < 4; k++)
            atomicAdd(&cnt[ei[N_EDGES + base + k * 256]], 1);
    } else if (bid < HIST_BLOCKS + PREPX_BLOCKS) {
        int t = (bid - HIST_BLOCKS) * 256 + tid;          // < N*32
        float4 v = reinterpret_cast<const float4*>(x)[t];
        unsigned int p0 = (unsigned int)f2bf(v.x) | ((unsigned int)f2bf(v.y) << 16);
        unsigned int p1 = (unsigned int)f2bf(v.z) | ((unsigned int)f2bf(v.w) << 16);
        int row = t >> 5, c = t & 31;
        reinterpret_cast<uint2*>(Abf_u)[(size_t)row * 64 + 32 + c] =
            make_uint2(p0, p1);
    } else {
        int t = (bid - HIST_BLOCKS - PREPX_BLOCKS) * 256 + tid;  // < 65536
        int k = t >> 8, n = t & 255;
        float v = (k < 128) ? Wl[k * 256 + n] : Wr[(k - 128) * 256 + n];
        Wimg[(size_t)(k >> 5) * 8192 + n * 32 + (k & 31)] = f2bf(v);
    }
}

// ---------------------------------------------------------------------------
// CSR build: scan + permute
// ---------------------------------------------------------------------------
__device__ inline int block_scan_excl(int v, int tid, int* tmp) {
    tmp[tid] = v;
    __syncthreads();
#pragma unroll
    for (int off = 1; off < 256; off <<= 1) {
        int t = (tid >= off) ? tmp[tid - off] : 0;
        __syncthreads();
        tmp[tid] += t;
        __syncthreads();
    }
    return tmp[tid] - v;
}

__global__ __launch_bounds__(256) void scan1_k(const int* __restrict__ cnt,
                                               int* __restrict__ blockSums) {
    __shared__ int tmp[256];
    int i = blockIdx.x * 256 + threadIdx.x;
    int v = (i < N_NODES) ? cnt[i] : 0;
    block_scan_excl(v, threadIdx.x, tmp);
    if (threadIdx.x == 255) blockSums[blockIdx.x] = tmp[255];
}

// scan23: each block reduces its own prefix of blockSums, then local scan.
__global__ __launch_bounds__(256) void scan23_k(const int* __restrict__ cnt,
                                                const int* __restrict__ blockSums,
                                                int* __restrict__ row_start,
                                                int* __restrict__ cursor) {
    __shared__ int red[256];
    __shared__ int tmp[256];
    int tid = threadIdx.x;
    int bv = (tid < (int)blockIdx.x) ? blockSums[tid] : 0;  // blockIdx < 256
    red[tid] = bv;
    __syncthreads();
#pragma unroll
    for (int off = 128; off > 0; off >>= 1) {
        if (tid < off) red[tid] += red[tid + off];
        __syncthreads();
    }
    int boff = red[0];
    int i = blockIdx.x * 256 + tid;
    int v = (i < N_NODES) ? cnt[i] : 0;
    int ex = block_scan_excl(v, tid, tmp);
    int rs = boff + ex;
    if (i < N_NODES) {
        row_start[i] = rs;
        cursor[i]    = rs;
    }
    if (i == N_NODES) row_start[N_NODES] = rs;
}

__global__ __launch_bounds__(256) void permute_k(const int* __restrict__ ei,
                                                 int* __restrict__ cursor,
                                                 int* __restrict__ sorted_src) {
    int e = blockIdx.x * 256 + threadIdx.x;
    if (e >= N_EDGES) return;
    int dst = ei[N_EDGES + e];
    int pos = atomicAdd(&cursor[dst], 1);
    sorted_src[pos] = ei[e];
}

// ---------------------------------------------------------------------------
// agg_k: one wave per node. Lane = (g, sub): g = edge subgroup (0..3),
// sub = 16B chunk of the 256B bf16 row.
// R5: prefetch up to 64 src indices with one coalesced load, broadcast via
// __shfl; 16 edges per iteration -> 4 independent gather loads in flight
// (4KB/wave). Cross-group reduce via shfl_xor(16/32) as before.
// ---------------------------------------------------------------------------
__global__ __launch_bounds__(256) void agg_k(const int* __restrict__ row_start,
                                             const int* __restrict__ sorted_src,
                                             unsigned int* __restrict__ Abf_u) {
    int wid  = (blockIdx.x * 256 + threadIdx.x) >> 6;  // node, < N exactly
    int lane = threadIdx.x & 63;
    int g    = lane >> 4;
    int sub  = lane & 15;
    int beg = row_start[wid];
    int end = row_start[wid + 1];
    int deg = end - beg;
    const uint4* X = reinterpret_cast<const uint4*>(Abf_u);  // row = 32 uint4

    float s[8];
#pragma unroll
    for (int j = 0; j < 8; j++) s[j] = 0.f;

    for (int base = 0; base < deg; base += 64) {
        int m = deg - base;
        if (m > 64) m = 64;
        // one coalesced load covers the whole batch of src indices
        int nsrc = (lane < m) ? sorted_src[beg + base + lane] : 0;

        for (int i = 0; i < m; i += 16) {
            int i0 = i + g;
            // register-only broadcast of the 4 edges this group handles
            int s0 = __shfl(nsrc, i0,      64);
            int s1 = __shfl(nsrc, i0 + 4,  64);
            int s2 = __shfl(nsrc, i0 + 8,  64);
            int s3 = __shfl(nsrc, i0 + 12, 64);
            uint4 z = make_uint4(0, 0, 0, 0);
            uint4 v0 = (i0      < m) ? X[(size_t)s0 * 32 + 16 + sub] : z;
            uint4 v1 = (i0 + 4  < m) ? X[(size_t)s1 * 32 + 16 + sub] : z;
            uint4 v2 = (i0 + 8  < m) ? X[(size_t)s2 * 32 + 16 + sub] : z;
            uint4 v3 = (i0 + 12 < m) ? X[(size_t)s3 * 32 + 16 + sub] : z;

            s[0] += (bf2f(v0.x & 0xffffu) + bf2f(v1.x & 0xffffu)) +
                    (bf2f(v2.x & 0xffffu) + bf2f(v3.x & 0xffffu));
            s[1] += (bf2f(v0.x >> 16)     + bf2f(v1.x >> 16)) +
                    (bf2f(v2.x >> 16)     + bf2f(v3.x >> 16));
            s[2] += (bf2f(v0.y & 0xffffu) + bf2f(v1.y & 0xffffu)) +
                    (bf2f(v2.y & 0xffffu) + bf2f(v3.y & 0xffffu));
            s[3] += (bf2f(v0.y >> 16)     + bf2f(v1.y >> 16)) +
                    (bf2f(v2.y >> 16)     + bf2f(v3.y >> 16));
            s[4] += (bf2f(v0.z & 0xffffu) + bf2f(v1.z & 0xffffu)) +
                    (bf2f(v2.z & 0xffffu) + bf2f(v3.z & 0xffffu));
            s[5] += (bf2f(v0.z >> 16)     + bf2f(v1.z >> 16)) +
                    (bf2f(v2.z >> 16)     + bf2f(v3.z >> 16));
            s[6] += (bf2f(v0.w & 0xffffu) + bf2f(v1.w & 0xffffu)) +
                    (bf2f(v2.w & 0xffffu) + bf2f(v3.w & 0xffffu));
            s[7] += (bf2f(v0.w >> 16)     + bf2f(v1.w >> 16)) +
                    (bf2f(v2.w >> 16)     + bf2f(v3.w >> 16));
        }
    }

#pragma unroll
    for (int m = 16; m <= 32; m <<= 1)
#pragma unroll
        for (int j = 0; j < 8; j++) s[j] += __shfl_xor(s[j], m, 64);

    if (g == 0) {
        float inv = (deg > 0) ? 1.0f / (float)deg : 0.0f;
        uint4 o;
        o.x = (unsigned int)f2bf(s[0] * inv) | ((unsigned int)f2bf(s[1] * inv) << 16);
        o.y = (unsigned int)f2bf(s[2] * inv) | ((unsigned int)f2bf(s[3] * inv) << 16);
        o.z = (unsigned int)f2bf(s[4] * inv) | ((unsigned int)f2bf(s[5] * inv) << 16);
        o.w = (unsigned int)f2bf(s[6] * inv) | ((unsigned int)f2bf(s[7] * inv) << 16);
        reinterpret_cast<uint4*>(Abf_u)[(size_t)wid * 32 + sub] = o;
    }
}

// ---------------------------------------------------------------------------
// gemm_k: out[N][256] = Abf[N][256] @ Wcat[256][256] + bl, bf16 MFMA.
// ---------------------------------------------------------------------------
__global__ __launch_bounds__(256) void gemm_k(const unsigned short* __restrict__ Abf,
                                              const unsigned short* __restrict__ Wimg,
                                              const float* __restrict__ bl,
                                              float* __restrict__ out) {
    __shared__ unsigned short As[64 * 40];    // rows padded to 40 bf16 (80B)
    __shared__ unsigned short Bs[256 * 40];

    int tid  = threadIdx.x;
    int w    = tid >> 6;
    int lane = tid & 63;
    int m15  = lane & 15;
    int quad = lane >> 4;
    int bm   = blockIdx.x * 64;

    f32x4 zero4 = {0.f, 0.f, 0.f, 0.f};
    f32x4 acc[4][4];
#pragma unroll
    for (int rt = 0; rt < 4; rt++)
#pragma unroll
        for (int ct = 0; ct < 4; ct++) acc[rt][ct] = zero4;

    for (int kc = 0; kc < 8; kc++) {
        {
            int row = tid >> 2, q = tid & 3;
            int grow = bm + row;
            short8 v = {0, 0, 0, 0, 0, 0, 0, 0};
            if (grow < N_NODES)
                v = *reinterpret_cast<const short8*>(
                        Abf + (size_t)grow * 256 + kc * 32 + q * 8);
            *reinterpret_cast<short8*>(As + row * 40 + q * 8) = v;
        }
        {
            const unsigned short* src = Wimg + (size_t)kc * 8192 + tid * 32;
#pragma unroll
            for (int s = 0; s < 4; s++) {
                short8 v = *reinterpret_cast<const short8*>(src + s * 8);
                *reinterpret_cast<short8*>(Bs + tid * 40 + s * 8) = v;
            }
        }
        __syncthreads();

        short8 Af[4], Bf[4];
#pragma unroll
        for (int rt = 0; rt < 4; rt++)
            Af[rt] = *reinterpret_cast<const short8*>(
                         As + (rt * 16 + m15) * 40 + quad * 8);
#pragma unroll
        for (int ct = 0; ct < 4; ct++)
            Bf[ct] = *reinterpret_cast<const short8*>(
                         Bs + (w * 64 + ct * 16 + m15) * 40 + quad * 8);
#pragma unroll
        for (int rt = 0; rt < 4; rt++)
#pragma unroll
            for (int ct = 0; ct < 4; ct++)
                acc[rt][ct] = __builtin_amdgcn_mfma_f32_16x16x32_bf16(
                    Af[rt], Bf[ct], acc[rt][ct], 0, 0, 0);
        __syncthreads();
    }

    float bias[4];
#pragma unroll
    for (int ct = 0; ct < 4; ct++) bias[ct] = bl[w * 64 + ct * 16 + m15];
#pragma unroll
    for (int rt = 0; rt < 4; rt++) {
        int rb = bm + rt * 16 + quad * 4;
#pragma unroll
        for (int r = 0; r < 4; r++) {
            int row = rb + r;
            if (row < N_NODES) {
#pragma unroll
                for (int ct = 0; ct < 4; ct++)
                    out[(size_t)row * 256 + w * 64 + ct * 16 + m15] =
                        acc[rt][ct][r] + bias[ct];
            }
        }
    }
}

extern "C" void kernel_launch(void* const* d_in, const int* in_sizes, int n_in,
                              void* d_out, int out_size, void* d_ws, size_t ws_size,
                              hipStream_t stream) {
    const float* x  = (const float*)d_in[0];
    const int*   ei = (const int*)d_in[1];   // [2, E] int32
    const float* Wl = (const float*)d_in[2];
    const float* bl = (const float*)d_in[3];
    const float* Wr = (const float*)d_in[4];
    float* out = (float*)d_out;

    // ws layout
    unsigned short* Abf  = (unsigned short*)d_ws;              // N*256 bf16
    unsigned short* Wimg = Abf + (size_t)N_NODES * 256;        // 65536 bf16
    int* cnt        = (int*)(Wimg + 65536);                    // N
    int* row_start  = cnt + N_NODES;                           // N+1
    int* cursor     = row_start + N_NODES + 1;                 // N
    int* blockSums  = cursor + N_NODES;                        // 256
    int* sorted_src = blockSums + 256;                         // E

    hipMemsetAsync(cnt, 0, N_NODES * sizeof(int), stream);

    prep_k<<<HIST_BLOCKS + PREPX_BLOCKS + WPREP_BLOCKS, 256, 0, stream>>>(
        x, ei, Wl, Wr, (unsigned int*)Abf, Wimg, cnt);
    scan1_k<<<SCAN_BLOCKS, 256, 0, stream>>>(cnt, blockSums);
    scan23_k<<<SCAN_BLOCKS, 256, 0, stream>>>(cnt, blockSums, row_start, cursor);
    permute_k<<<(N_EDGES + 255) / 256, 256, 0, stream>>>(ei, cursor, sorted_src);
    agg_k<<<(N_NODES * 64) / 256, 256, 0, stream>>>(row_start, sorted_src,
                                                    (unsigned int*)Abf);
    gemm_k<<<(N_NODES + 63) / 64, 256, 0, stream>>>(Abf, Wimg, bl, out);
}

// Round 2
// 208.367 us; speedup vs baseline: 1.0519x; 1.0519x over previous
//
#include <hip/hip_runtime.h>

// SimpleGraphSAGE: out = mean_agg(x[src]->dst) @ W_l + b_l + x @ W_r
// N=50000, E=640000, IN=128, HID=256.
// R6: (a) whole 16-bit pipeline bf16 -> fp16 (better precision, and enables
//     v_pk_add_f16 accumulation in agg: ~4x VALU cut; GEMM uses
//     mfma_f32_16x16x32_f16, same rate/layout as bf16).
//     (b) agg_k: 4 nodes per wave, 16 lanes own one node each -> no cross-
//     group reduce, full-wave coalesced 1KB store, per-group predication
//     (no wasted 16-slot batches), 8 independent gather chains in flight.

constexpr int N_NODES = 50000;
constexpr int N_EDGES = 640000;
constexpr int IN_CH   = 128;
constexpr int HID_CH  = 256;
constexpr int SCAN_BLOCKS = (N_NODES + 256) / 256;  // 196, covers i==N_NODES

constexpr int HIST_BLOCKS  = N_EDGES / 1024;        // 625, thread handles 4 edges
constexpr int PREPX_BLOCKS = N_NODES * 32 / 256;    // 6250, thread = 4 channels
constexpr int WPREP_BLOCKS = 256;                   // 65536 weight elems

typedef __attribute__((ext_vector_type(8))) short short8;
typedef __attribute__((ext_vector_type(4))) float f32x4;
typedef _Float16 half8 __attribute__((ext_vector_type(8)));

__device__ inline unsigned short f2h(float f) {
    _Float16 h = (_Float16)f;               // v_cvt_f16_f32, RNE
    return __builtin_bit_cast(unsigned short, h);
}

// ---------------------------------------------------------------------------
// prep_k: block-range fused  [hist | x->fp16 | W->fp16 tiled]
// ---------------------------------------------------------------------------
__global__ __launch_bounds__(256) void prep_k(const float* __restrict__ x,
                                              const int* __restrict__ ei,
                                              const float* __restrict__ Wl,
                                              const float* __restrict__ Wr,
                                              unsigned int* __restrict__ Abf_u,
                                              unsigned short* __restrict__ Wimg,
                                              int* __restrict__ cnt) {
    int bid = blockIdx.x, tid = threadIdx.x;
    if (bid < HIST_BLOCKS) {
        int base = bid * 1024 + tid;
#pragma unroll
        for (int k = 0; k < 4; k++)
            atomicAdd(&cnt[ei[N_EDGES + base + k * 256]], 1);
    } else if (bid < HIST_BLOCKS + PREPX_BLOCKS) {
        int t = (bid - HIST_BLOCKS) * 256 + tid;          // < N*32
        float4 v = reinterpret_cast<const float4*>(x)[t];
        unsigned int p0 = (unsigned int)f2h(v.x) | ((unsigned int)f2h(v.y) << 16);
        unsigned int p1 = (unsigned int)f2h(v.z) | ((unsigned int)f2h(v.w) << 16);
        int row = t >> 5, c = t & 31;
        reinterpret_cast<uint2*>(Abf_u)[(size_t)row * 64 + 32 + c] =
            make_uint2(p0, p1);
    } else {
        int t = (bid - HIST_BLOCKS - PREPX_BLOCKS) * 256 + tid;  // < 65536
        int k = t >> 8, n = t & 255;
        float v = (k < 128) ? Wl[k * 256 + n] : Wr[(k - 128) * 256 + n];
        Wimg[(size_t)(k >> 5) * 8192 + n * 32 + (k & 31)] = f2h(v);
    }
}

// ---------------------------------------------------------------------------
// CSR build: scan + permute
// ---------------------------------------------------------------------------
__device__ inline int block_scan_excl(int v, int tid, int* tmp) {
    tmp[tid] = v;
    __syncthreads();
#pragma unroll
    for (int off = 1; off < 256; off <<= 1) {
        int t = (tid >= off) ? tmp[tid - off] : 0;
        __syncthreads();
        tmp[tid] += t;
        __syncthreads();
    }
    return tmp[tid] - v;
}

__global__ __launch_bounds__(256) void scan1_k(const int* __restrict__ cnt,
                                               int* __restrict__ blockSums) {
    __shared__ int tmp[256];
    int i = blockIdx.x * 256 + threadIdx.x;
    int v = (i < N_NODES) ? cnt[i] : 0;
    block_scan_excl(v, threadIdx.x, tmp);
    if (threadIdx.x == 255) blockSums[blockIdx.x] = tmp[255];
}

// scan23: each block reduces its own prefix of blockSums, then local scan.
__global__ __launch_bounds__(256) void scan23_k(const int* __restrict__ cnt,
                                                const int* __restrict__ blockSums,
                                                int* __restrict__ row_start,
                                                int* __restrict__ cursor) {
    __shared__ int red[256];
    __shared__ int tmp[256];
    int tid = threadIdx.x;
    int bv = (tid < (int)blockIdx.x) ? blockSums[tid] : 0;  // blockIdx < 256
    red[tid] = bv;
    __syncthreads();
#pragma unroll
    for (int off = 128; off > 0; off >>= 1) {
        if (tid < off) red[tid] += red[tid + off];
        __syncthreads();
    }
    int boff = red[0];
    int i = blockIdx.x * 256 + tid;
    int v = (i < N_NODES) ? cnt[i] : 0;
    int ex = block_scan_excl(v, tid, tmp);
    int rs = boff + ex;
    if (i < N_NODES) {
        row_start[i] = rs;
        cursor[i]    = rs;
    }
    if (i == N_NODES) row_start[N_NODES] = rs;
}

__global__ __launch_bounds__(256) void permute_k(const int* __restrict__ ei,
                                                 int* __restrict__ cursor,
                                                 int* __restrict__ sorted_src) {
    int e = blockIdx.x * 256 + threadIdx.x;
    if (e >= N_EDGES) return;
    int dst = ei[N_EDGES + e];
    int pos = atomicAdd(&cursor[dst], 1);
    sorted_src[pos] = ei[e];
}

// ---------------------------------------------------------------------------
// agg_k (R6): 4 nodes per wave. Lane = (g, sub): g = node subgroup (0..3)
// owning node wid*4+g, sub = 16B chunk of that node's 256B fp16 row.
// Per 16-edge batch: 2 half-batches of 8 predicated idx->row gather chains
// (8KB in flight), fp16 tree accumulate via v_pk_add_f16. No cross-group
// reduce; full-wave 1KB coalesced store.
// ---------------------------------------------------------------------------
__global__ __launch_bounds__(256) void agg_k(const int* __restrict__ row_start,
                                             const int* __restrict__ sorted_src,
                                             unsigned int* __restrict__ Abf_u) {
    int wave = (blockIdx.x * 256 + threadIdx.x) >> 6;  // 0..12499
    int lane = threadIdx.x & 63;
    int g    = lane >> 4;
    int sub  = lane & 15;
    int node = wave * 4 + g;                           // N divisible by 4
    int beg  = row_start[node];
    int end  = row_start[node + 1];
    int deg  = end - beg;
    const half8* X8 = reinterpret_cast<const half8*>(Abf_u);  // row = 32 half8

    half8 acc = {0, 0, 0, 0, 0, 0, 0, 0};

#define LOADV(vj, J)                                                    \
    half8 vj = {0, 0, 0, 0, 0, 0, 0, 0};                                \
    if (base + (J) < deg)                                               \
        vj = X8[(size_t)sorted_src[beg + base + (J)] * 32 + 16 + sub];

    for (int base = 0; base < deg; base += 16) {
        {
            LOADV(v0, 0) LOADV(v1, 1) LOADV(v2, 2) LOADV(v3, 3)
            LOADV(v4, 4) LOADV(v5, 5) LOADV(v6, 6) LOADV(v7, 7)
            acc += ((v0 + v1) + (v2 + v3)) + ((v4 + v5) + (v6 + v7));
        }
        {
            LOADV(v0, 8)  LOADV(v1, 9)  LOADV(v2, 10) LOADV(v3, 11)
            LOADV(v4, 12) LOADV(v5, 13) LOADV(v6, 14) LOADV(v7, 15)
            acc += ((v0 + v1) + (v2 + v3)) + ((v4 + v5) + (v6 + v7));
        }
    }
#undef LOADV

    float inv = (deg > 0) ? 1.0f / (float)deg : 0.0f;
    half8 o;
#pragma unroll
    for (int j = 0; j < 8; j++) o[j] = (_Float16)((float)acc[j] * inv);
    reinterpret_cast<half8*>(Abf_u)[(size_t)node * 32 + sub] = o;
}

// ---------------------------------------------------------------------------
// gemm_k: out[N][256] = Abf[N][256] @ Wcat[256][256] + bl, fp16 MFMA.
// ---------------------------------------------------------------------------
__global__ __launch_bounds__(256) void gemm_k(const unsigned short* __restrict__ Abf,
                                              const unsigned short* __restrict__ Wimg,
                                              const float* __restrict__ bl,
                                              float* __restrict__ out) {
    __shared__ unsigned short As[64 * 40];    // rows padded to 40 elems (80B)
    __shared__ unsigned short Bs[256 * 40];

    int tid  = threadIdx.x;
    int w    = tid >> 6;
    int lane = tid & 63;
    int m15  = lane & 15;
    int quad = lane >> 4;
    int bm   = blockIdx.x * 64;

    f32x4 zero4 = {0.f, 0.f, 0.f, 0.f};
    f32x4 acc[4][4];
#pragma unroll
    for (int rt = 0; rt < 4; rt++)
#pragma unroll
        for (int ct = 0; ct < 4; ct++) acc[rt][ct] = zero4;

    for (int kc = 0; kc < 8; kc++) {
        {
            int row = tid >> 2, q = tid & 3;
            int grow = bm + row;
            short8 v = {0, 0, 0, 0, 0, 0, 0, 0};
            if (grow < N_NODES)
                v = *reinterpret_cast<const short8*>(
                        Abf + (size_t)grow * 256 + kc * 32 + q * 8);
            *reinterpret_cast<short8*>(As + row * 40 + q * 8) = v;
        }
        {
            const unsigned short* src = Wimg + (size_t)kc * 8192 + tid * 32;
#pragma unroll
            for (int s = 0; s < 4; s++) {
                short8 v = *reinterpret_cast<const short8*>(src + s * 8);
                *reinterpret_cast<short8*>(Bs + tid * 40 + s * 8) = v;
            }
        }
        __syncthreads();

        half8 Af[4], Bf[4];
#pragma unroll
        for (int rt = 0; rt < 4; rt++)
            Af[rt] = *reinterpret_cast<const half8*>(
                         As + (rt * 16 + m15) * 40 + quad * 8);
#pragma unroll
        for (int ct = 0; ct < 4; ct++)
            Bf[ct] = *reinterpret_cast<const half8*>(
                         Bs + (w * 64 + ct * 16 + m15) * 40 + quad * 8);
#pragma unroll
        for (int rt = 0; rt < 4; rt++)
#pragma unroll
            for (int ct = 0; ct < 4; ct++)
                acc[rt][ct] = __builtin_amdgcn_mfma_f32_16x16x32_f16(
                    Af[rt], Bf[ct], acc[rt][ct], 0, 0, 0);
        __syncthreads();
    }

    float bias[4];
#pragma unroll
    for (int ct = 0; ct < 4; ct++) bias[ct] = bl[w * 64 + ct * 16 + m15];
#pragma unroll
    for (int rt = 0; rt < 4; rt++) {
        int rb = bm + rt * 16 + quad * 4;
#pragma unroll
        for (int r = 0; r < 4; r++) {
            int row = rb + r;
            if (row < N_NODES) {
#pragma unroll
                for (int ct = 0; ct < 4; ct++)
                    out[(size_t)row * 256 + w * 64 + ct * 16 + m15] =
                        acc[rt][ct][r] + bias[ct];
            }
        }
    }
}

extern "C" void kernel_launch(void* const* d_in, const int* in_sizes, int n_in,
                              void* d_out, int out_size, void* d_ws, size_t ws_size,
                              hipStream_t stream) {
    const float* x  = (const float*)d_in[0];
    const int*   ei = (const int*)d_in[1];   // [2, E] int32
    const float* Wl = (const float*)d_in[2];
    const float* bl = (const float*)d_in[3];
    const float* Wr = (const float*)d_in[4];
    float* out = (float*)d_out;

    // ws layout
    unsigned short* Abf  = (unsigned short*)d_ws;              // N*256 fp16
    unsigned short* Wimg = Abf + (size_t)N_NODES * 256;        // 65536 fp16
    int* cnt        = (int*)(Wimg + 65536);                    // N
    int* row_start  = cnt + N_NODES;                           // N+1
    int* cursor     = row_start + N_NODES + 1;                 // N
    int* blockSums  = cursor + N_NODES;                        // 256
    int* sorted_src = blockSums + 256;                         // E

    hipMemsetAsync(cnt, 0, N_NODES * sizeof(int), stream);

    prep_k<<<HIST_BLOCKS + PREPX_BLOCKS + WPREP_BLOCKS, 256, 0, stream>>>(
        x, ei, Wl, Wr, (unsigned int*)Abf, Wimg, cnt);
    scan1_k<<<SCAN_BLOCKS, 256, 0, stream>>>(cnt, blockSums);
    scan23_k<<<SCAN_BLOCKS, 256, 0, stream>>>(cnt, blockSums, row_start, cursor);
    permute_k<<<(N_EDGES + 255) / 256, 256, 0, stream>>>(ei, cursor, sorted_src);
    agg_k<<<(N_NODES / 4 * 64) / 256, 256, 0, stream>>>(row_start, sorted_src,
                                                        (unsigned int*)Abf);
    gemm_k<<<(N_NODES + 63) / 64, 256, 0, stream>>>(Abf, Wimg, bl, out);
}